// Round 7
// baseline (15812.491 us; speedup 1.0000x reference)
//
#include <hip/hip_runtime.h>
#include <hip/hip_bf16.h>

// B=32, T=128, I=H=O=512, L=2 bidir GRU + FC.
// R7: persistent pipeline kernel. Weights LDS-resident (staged once), 130 ticks
// with in-kernel grid barrier (counter + s_sleep poll) + threadfence release/acquire.
// ws layout:
//   proj0 (bf16): 12,582,912 e * 2B = 25,165,824 B
//   seq0  (fp32): 4,194,304 f
//   rslabs(fp32): 3,145,728 f
//   islabs(fp32): 1,572,864 f
//   p1    (fp32): 196,608 f
//   h1ring(fp32): 65,536 f
//   fcin  (fp32): 32,768 f
//   arrive(int) : 256
// total ~62 MB

// ---------------- proj GEMM (layer 0 only): [8192 x 1536] -> bf16 ----------------
__global__ __launch_bounds__(256)
void proj_kernel(const float* __restrict__ src,
                 const float* __restrict__ Wxh, const float* __restrict__ bxh,
                 const float* __restrict__ Wxr, const float* __restrict__ bxr,
                 __hip_bfloat16* __restrict__ proj)
{
    __shared__ float As[32][137];
    __shared__ float Ws[32][132];
    const int tid  = threadIdx.x;
    const int col0 = blockIdx.x * 128;
    const int row0 = blockIdx.y * 128;
    const int d    = row0 >> 12;
    const int tx = tid & 15, ty = tid >> 4;

    const bool is_xr = (col0 >= 1024);
    const float* Wbase = is_xr ? (Wxr + (size_t)d * 512 * 512 + (col0 - 1024))
                               : (Wxh + (size_t)d * 512 * 1024 + col0);
    const int wstride = is_xr ? 512 : 1024;
    const float* bias = is_xr ? (bxr + d * 512 + (col0 - 1024))
                              : (bxh + d * 1024 + col0);

    float acc[8][8];
    #pragma unroll
    for (int i = 0; i < 8; i++)
        #pragma unroll
        for (int j = 0; j < 8; j++) acc[i][j] = 0.f;

    for (int k0 = 0; k0 < 512; k0 += 32) {
        #pragma unroll
        for (int v = 0; v < 4; v++) {
            int idx = tid + v * 256;
            int r   = idx >> 3;
            int c4  = (idx & 7) << 2;
            int gm  = row0 + r;
            int rr  = gm & 4095;
            int tt  = rr >> 5, bb = rr & 31;
            int ts  = (gm >= 4096) ? (127 - tt) : tt;   // dir1 reads reversed time
            const float* p = src + ((size_t)bb * 128 + ts) * 512 + (k0 + c4);
            float4 vv = *(const float4*)p;
            As[c4 + 0][r] = vv.x; As[c4 + 1][r] = vv.y;
            As[c4 + 2][r] = vv.z; As[c4 + 3][r] = vv.w;
        }
        #pragma unroll
        for (int v = 0; v < 4; v++) {
            int idx = tid + v * 256;
            int kr  = idx >> 5;
            int c4  = (idx & 31) << 2;
            *(float4*)&Ws[kr][c4] = *(const float4*)(Wbase + (size_t)(k0 + kr) * wstride + c4);
        }
        __syncthreads();
        #pragma unroll
        for (int kk = 0; kk < 32; kk++) {
            float a[8], w[8];
            *(float4*)&a[0] = *(const float4*)&As[kk][ty * 8];
            *(float4*)&a[4] = *(const float4*)&As[kk][ty * 8 + 4];
            *(float4*)&w[0] = *(const float4*)&Ws[kk][tx * 8];
            *(float4*)&w[4] = *(const float4*)&Ws[kk][tx * 8 + 4];
            #pragma unroll
            for (int i = 0; i < 8; i++)
                #pragma unroll
                for (int j = 0; j < 8; j++)
                    acc[i][j] += a[i] * w[j];
        }
        __syncthreads();
    }
    #pragma unroll
    for (int i = 0; i < 8; i++) {
        int gm = row0 + ty * 8 + i;
        __hip_bfloat16* dst = proj + (size_t)gm * 1536 + col0 + tx * 8;
        #pragma unroll
        for (int j = 0; j < 8; j++)
            dst[j] = __float2bfloat16(acc[i][j] + bias[tx * 8 + j]);
    }
}

// ---------------- recur weight repack (both layers): slab[(ld*128+jb)] ----------------
__global__ __launch_bounds__(256)
void repack_kernel(const float* __restrict__ Whh, const float* __restrict__ Whr,
                   float* __restrict__ slabs)
{
    const int blk = blockIdx.x;           // 0..511 = ld*128 + jb
    const int ld = blk >> 7, jb = blk & 127;
    const float* WhhL = Whh + (size_t)ld * 512 * 1024;
    const float* WhrL = Whr + (size_t)ld * 512 * 512;
    float* out = slabs + (size_t)blk * 6144;
    for (int u = 0; u < 24; u++) {
        int idx = threadIdx.x + u * 256;
        int rec = idx / 12, r3 = idx % 12;
        int g = rec >> 2, cg = rec & 3;
        int e = r3 >> 2, ki = r3 & 3;
        int k = g * 4 + ki, j = jb * 4 + cg;
        float v;
        if (e == 0)      v = WhhL[(size_t)k * 1024 + j];
        else if (e == 1) v = WhhL[(size_t)k * 1024 + 512 + j];
        else             v = WhrL[(size_t)k * 512 + j];
        out[idx] = v;
    }
}

// ---------------- layer-1 input-proj weight repack: islabs[(d*128+cb)] ----------------
__global__ __launch_bounds__(256)
void irepack_kernel(const float* __restrict__ Wxh, const float* __restrict__ Wxr,
                    float* __restrict__ islabs)
{
    const int blk = blockIdx.x;           // 0..255 = d*128 + cb
    const int d = blk >> 7, cb = blk & 127;
    const float* WxhL = Wxh + (size_t)(2 + d) * 512 * 1024;
    const float* WxrL = Wxr + (size_t)(2 + d) * 512 * 512;
    float* out = islabs + (size_t)blk * 6144;
    for (int u = 0; u < 24; u++) {
        int idx = threadIdx.x + u * 256;
        int rec = idx / 12, r3 = idx % 12;
        int g = rec >> 2, cg = rec & 3;
        int e = r3 >> 2, ki = r3 & 3;
        int k = g * 4 + ki, c = cb * 12 + cg * 3 + e;
        out[idx] = (c < 1024) ? WxhL[(size_t)k * 1024 + c]
                              : WxrL[(size_t)k * 512 + (c - 1024)];
    }
}

// ---------------- persistent pipeline kernel ----------------
// grid 512 (2 blocks/CU guaranteed): blk<256 = group A (L0-recur),
// blk>=256 = group B (L1-recur then L1-inproj). Weights in LDS, staged once.
__global__ __launch_bounds__(256, 2)
void persist_kernel(const __hip_bfloat16* __restrict__ proj0, float* __restrict__ seq0,
                    const float* __restrict__ rslabs, const float* __restrict__ islabs,
                    float* __restrict__ p1, float* __restrict__ h1ring,
                    float* __restrict__ fcin,
                    const float* __restrict__ bhh, const float* __restrict__ bhr,
                    const float* __restrict__ bxh, const float* __restrict__ bxr,
                    int* __restrict__ arrive)
{
    __shared__ __align__(16) float wlds[12288];   // [0..6143]=recur slab, [6144..]=inproj slab (B)
    const int blk = blockIdx.x, tid = threadIdx.x;
    const bool isA = blk < 256;
    const int d  = (blk & 255) >> 7;
    const int jb = blk & 127;
    const int cg = tid & 3, kh = (tid >> 2) & 1, b = tid >> 3;
    const int j  = jb * 4 + cg;

    // ---- stage weights into LDS (once) ----
    {
        const float4* rs = (const float4*)(rslabs + (size_t)((isA ? d : 2 + d) * 128 + jb) * 6144);
        #pragma unroll
        for (int v = 0; v < 6; v++) {
            int id = tid + v * 256;
            *(float4*)&wlds[id * 4] = rs[id];
        }
        if (!isA) {
            const float4* is_ = (const float4*)(islabs + (size_t)(d * 128 + jb) * 6144);
            #pragma unroll
            for (int v = 0; v < 6; v++) {
                int id = tid + v * 256;
                *(float4*)&wlds[6144 + id * 4] = is_[id];
            }
        }
    }
    // ---- invariant biases ----
    const int ld = isA ? d : 2 + d;
    const float bz  = bhh[ld * 1024 + j];
    const float brr = bhh[ld * 1024 + 512 + j];
    const float bgg = bhr[ld * 512 + j];
    const int c0 = jb * 12 + cg * 3;
    float bi0 = 0.f, bi1 = 0.f, bi2 = 0.f;
    if (!isA) {
        float bv[3];
        #pragma unroll
        for (int e = 0; e < 3; e++) {
            int c = c0 + e;
            bv[e] = (c < 1024) ? bxh[(size_t)(2 + d) * 1024 + c]
                               : bxr[(size_t)(2 + d) * 512 + (c - 1024)];
        }
        bi0 = bv[0]; bi1 = bv[1]; bi2 = bv[2];
    }
    __syncthreads();

    for (int t = 0; t < 130; t++) {
        if (isA) {
            // ---- layer 0 recurrence, step t ----
            if (t <= 127) {
                float az = 0.f, ar = 0.f, ag = 0.f, hself = 0.f;
                if (t > 0) {
                    const float* hrow = seq0 + (size_t)(d * 128 + (t - 1)) * 32 * 512 + (size_t)b * 512;
                    #pragma unroll 8
                    for (int gg = 0; gg < 64; gg++) {
                        int g = kh * 64 + gg;
                        float4 h4 = *(const float4*)(hrow + g * 4);
                        const float4* wp = (const float4*)wlds + (size_t)(g * 4 + cg) * 3;
                        float4 wz = wp[0], wr = wp[1], wg = wp[2];
                        az += h4.x*wz.x + h4.y*wz.y + h4.z*wz.z + h4.w*wz.w;
                        ar += h4.x*wr.x + h4.y*wr.y + h4.z*wr.z + h4.w*wr.w;
                        ag += h4.x*wg.x + h4.y*wg.y + h4.z*wg.z + h4.w*wg.w;
                    }
                    az += __shfl_xor(az, 4, 64);
                    ar += __shfl_xor(ar, 4, 64);
                    ag += __shfl_xor(ag, 4, 64);
                    hself = hrow[j];
                }
                const __hip_bfloat16* pp = proj0 + (size_t)(d * 128 + t) * 32 * 1536 + (size_t)b * 1536;
                float pz = __bfloat162float(pp[j]);
                float pr = __bfloat162float(pp[512 + j]);
                float pg = __bfloat162float(pp[1024 + j]);
                float z  = 1.f / (1.f + __expf(-(az + pz + bz)));
                float r  = 1.f / (1.f + __expf(-(ar + pr + brr)));
                float gt = tanhf((ag + bgg) * r + pg);
                float hn = z * hself + (1.f - z) * gt;
                if (kh == 0)
                    seq0[(size_t)(d * 128 + t) * 32 * 512 + (size_t)b * 512 + j] = hn;
            }
        } else {
            // ---- layer 1 recurrence, step t1 = t-2 ----
            const int t1 = t - 2;
            if (t1 >= 0) {
                float az = 0.f, ar = 0.f, ag = 0.f, hself = 0.f;
                if (t1 > 0) {
                    const float* hrow = h1ring + (size_t)((((t1 - 1) & 1) * 2) + d) * 32 * 512 + (size_t)b * 512;
                    #pragma unroll 8
                    for (int gg = 0; gg < 64; gg++) {
                        int g = kh * 64 + gg;
                        float4 h4 = *(const float4*)(hrow + g * 4);
                        const float4* wp = (const float4*)wlds + (size_t)(g * 4 + cg) * 3;
                        float4 wz = wp[0], wr = wp[1], wg = wp[2];
                        az += h4.x*wz.x + h4.y*wz.y + h4.z*wz.z + h4.w*wz.w;
                        ar += h4.x*wr.x + h4.y*wr.y + h4.z*wr.z + h4.w*wr.w;
                        ag += h4.x*wg.x + h4.y*wg.y + h4.z*wg.z + h4.w*wg.w;
                    }
                    az += __shfl_xor(az, 4, 64);
                    ar += __shfl_xor(ar, 4, 64);
                    ag += __shfl_xor(ag, 4, 64);
                    hself = hrow[j];
                }
                const float* pp = p1 + (size_t)(((t1 & 1) * 2) + d) * 32 * 1536 + (size_t)b * 1536;
                float z  = 1.f / (1.f + __expf(-(az + pp[j] + bz)));
                float r  = 1.f / (1.f + __expf(-(ar + pp[512 + j] + brr)));
                float gt = tanhf((ag + bgg) * r + pp[1024 + j]);
                float hn = z * hself + (1.f - z) * gt;
                if (kh == 0) {
                    h1ring[(size_t)(((t1 & 1) * 2) + d) * 32 * 512 + (size_t)b * 512 + j] = hn;
                    if (d == 0 && t1 == 127) fcin[(size_t)b * 512 + j] = hn;
                    if (d == 1 && t1 == 0)   fcin[32 * 512 + (size_t)b * 512 + j] = hn;
                }
            }
            // ---- layer 1 input proj, step tp = t-1 ----
            const int tp = t - 1;
            if (tp >= 0 && tp <= 127) {
                const float* xrow = seq0 + (size_t)(d * 128 + tp) * 32 * 512 + (size_t)b * 512;
                float a0 = 0.f, a1 = 0.f, a2 = 0.f;
                #pragma unroll 8
                for (int gg = 0; gg < 64; gg++) {
                    int g = kh * 64 + gg;
                    float4 h4 = *(const float4*)(xrow + g * 4);
                    const float4* wp = (const float4*)(wlds + 6144) + (size_t)(g * 4 + cg) * 3;
                    float4 w0 = wp[0], w1 = wp[1], w2 = wp[2];
                    a0 += h4.x*w0.x + h4.y*w0.y + h4.z*w0.z + h4.w*w0.w;
                    a1 += h4.x*w1.x + h4.y*w1.y + h4.z*w1.z + h4.w*w1.w;
                    a2 += h4.x*w2.x + h4.y*w2.y + h4.z*w2.z + h4.w*w2.w;
                }
                a0 += __shfl_xor(a0, 4, 64);
                a1 += __shfl_xor(a1, 4, 64);
                a2 += __shfl_xor(a2, 4, 64);
                if (kh == 0) {
                    float* dst = p1 + (size_t)(((tp & 1) * 2) + d) * 32 * 1536 + (size_t)b * 1536 + c0;
                    dst[0] = a0 + bi0; dst[1] = a1 + bi1; dst[2] = a2 + bi2;
                }
            }
        }
        // ---- grid barrier (skip after last tick) ----
        if (t < 129) {
            __syncthreads();      // drain this block's stores (vmcnt0 + barrier)
            __threadfence();      // release: writeback L2 to coherence point
            if (tid == 0) {
                __hip_atomic_fetch_add(&arrive[t], 1, __ATOMIC_RELEASE, __HIP_MEMORY_SCOPE_AGENT);
                while (__hip_atomic_load(&arrive[t], __ATOMIC_RELAXED, __HIP_MEMORY_SCOPE_AGENT) < 512)
                    __builtin_amdgcn_s_sleep(16);
            }
            __syncthreads();
            __threadfence();      // acquire: invalidate stale L2 before next tick's reads
        }
    }
}

// ---------------- final FC ----------------
__global__ __launch_bounds__(256)
void fc_kernel(const float* __restrict__ fcin, const float* __restrict__ Wfc,
               const float* __restrict__ bfc, float* __restrict__ out)
{
    int idx = blockIdx.x * 256 + threadIdx.x;   // 0..16383
    int b = idx >> 9, o = idx & 511;
    const float* catf = fcin + (size_t)b * 512;
    const float* catr = fcin + 32 * 512 + (size_t)b * 512;
    float acc = bfc[o];
    #pragma unroll 8
    for (int k = 0; k < 512; k++) acc += catf[k] * Wfc[(size_t)k * 512 + o];
    #pragma unroll 8
    for (int k = 0; k < 512; k++) acc += catr[k] * Wfc[(size_t)(512 + k) * 512 + o];
    out[(size_t)b * 512 + o] = acc;
}

extern "C" void kernel_launch(void* const* d_in, const int* in_sizes, int n_in,
                              void* d_out, int out_size, void* d_ws, size_t ws_size,
                              hipStream_t stream) {
    (void)in_sizes; (void)n_in; (void)out_size; (void)ws_size;
    const float* x   = (const float*)d_in[0];
    const float* Wxh = (const float*)d_in[1];
    const float* bxh = (const float*)d_in[2];
    const float* Whh = (const float*)d_in[3];
    const float* bhh = (const float*)d_in[4];
    const float* Wxr = (const float*)d_in[5];
    const float* bxr = (const float*)d_in[6];
    const float* Whr = (const float*)d_in[7];
    const float* bhr = (const float*)d_in[8];
    const float* Wfc = (const float*)d_in[9];
    const float* bfc = (const float*)d_in[10];
    float* out = (float*)d_out;

    char* base = (char*)d_ws;
    __hip_bfloat16* proj0 = (__hip_bfloat16*)base;
    float* seq0   = (float*)(base + 25165824);
    float* rslabs = seq0   + 4194304;
    float* islabs = rslabs + 3145728;
    float* p1     = islabs + 1572864;
    float* h1ring = p1     + 196608;
    float* fcin   = h1ring + 65536;
    int*   arrive = (int*)(fcin + 32768);

    hipMemsetAsync(arrive, 0, 256 * sizeof(int), stream);

    repack_kernel<<<512, 256, 0, stream>>>(Whh, Whr, rslabs);
    irepack_kernel<<<256, 256, 0, stream>>>(Wxh, Wxr, islabs);

    dim3 pgrid(12, 64);
    proj_kernel<<<pgrid, 256, 0, stream>>>(x, Wxh, bxh, Wxr, bxr, proj0);

    persist_kernel<<<512, 256, 0, stream>>>(proj0, seq0, rslabs, islabs, p1,
                                            h1ring, fcin, bhh, bhr, bxh, bxr, arrive);

    fc_kernel<<<64, 256, 0, stream>>>(fcin, Wfc, bfc, out);
}

// Round 8
// 12948.811 us; speedup vs baseline: 1.2212x; 1.2212x over previous
//
#include <hip/hip_runtime.h>
#include <hip/hip_bf16.h>

// B=32, T=128, I=H=O=512, L=2 bidir GRU + FC.
// R8: persistent pipeline v2. Weights LDS-resident (24KB/block, staged once).
// Cross-block exchange: sc0sc1 write-through atomic stores + plain (L2-cached) loads.
// Barrier: 1 thread/block, 8 spread counters/tick, RELEASE add + ACQUIRE load (1 inv/blk/tick).
// Grid 768 = A: L0-recur(256) | B: L1-recur(256) | C: L1-inproj(256); 3 blocks/CU resident.
// ws layout (same as R7, arrive enlarged):
//   proj0 (bf16): 25,165,824 B ; seq0 4,194,304 f ; rslabs 3,145,728 f ;
//   islabs 1,572,864 f ; p1 196,608 f ; h1ring 65,536 f ; fcin 32,768 f ; arrive 2048 int

// ---------------- proj GEMM (layer 0 only): [8192 x 1536] -> bf16 ----------------
__global__ __launch_bounds__(256)
void proj_kernel(const float* __restrict__ src,
                 const float* __restrict__ Wxh, const float* __restrict__ bxh,
                 const float* __restrict__ Wxr, const float* __restrict__ bxr,
                 __hip_bfloat16* __restrict__ proj)
{
    __shared__ float As[32][137];
    __shared__ float Ws[32][132];
    const int tid  = threadIdx.x;
    const int col0 = blockIdx.x * 128;
    const int row0 = blockIdx.y * 128;
    const int d    = row0 >> 12;
    const int tx = tid & 15, ty = tid >> 4;

    const bool is_xr = (col0 >= 1024);
    const float* Wbase = is_xr ? (Wxr + (size_t)d * 512 * 512 + (col0 - 1024))
                               : (Wxh + (size_t)d * 512 * 1024 + col0);
    const int wstride = is_xr ? 512 : 1024;
    const float* bias = is_xr ? (bxr + d * 512 + (col0 - 1024))
                              : (bxh + d * 1024 + col0);

    float acc[8][8];
    #pragma unroll
    for (int i = 0; i < 8; i++)
        #pragma unroll
        for (int j = 0; j < 8; j++) acc[i][j] = 0.f;

    for (int k0 = 0; k0 < 512; k0 += 32) {
        #pragma unroll
        for (int v = 0; v < 4; v++) {
            int idx = tid + v * 256;
            int r   = idx >> 3;
            int c4  = (idx & 7) << 2;
            int gm  = row0 + r;
            int rr  = gm & 4095;
            int tt  = rr >> 5, bb = rr & 31;
            int ts  = (gm >= 4096) ? (127 - tt) : tt;   // dir1 reads reversed time
            const float* p = src + ((size_t)bb * 128 + ts) * 512 + (k0 + c4);
            float4 vv = *(const float4*)p;
            As[c4 + 0][r] = vv.x; As[c4 + 1][r] = vv.y;
            As[c4 + 2][r] = vv.z; As[c4 + 3][r] = vv.w;
        }
        #pragma unroll
        for (int v = 0; v < 4; v++) {
            int idx = tid + v * 256;
            int kr  = idx >> 5;
            int c4  = (idx & 31) << 2;
            *(float4*)&Ws[kr][c4] = *(const float4*)(Wbase + (size_t)(k0 + kr) * wstride + c4);
        }
        __syncthreads();
        #pragma unroll
        for (int kk = 0; kk < 32; kk++) {
            float a[8], w[8];
            *(float4*)&a[0] = *(const float4*)&As[kk][ty * 8];
            *(float4*)&a[4] = *(const float4*)&As[kk][ty * 8 + 4];
            *(float4*)&w[0] = *(const float4*)&Ws[kk][tx * 8];
            *(float4*)&w[4] = *(const float4*)&Ws[kk][tx * 8 + 4];
            #pragma unroll
            for (int i = 0; i < 8; i++)
                #pragma unroll
                for (int j = 0; j < 8; j++)
                    acc[i][j] += a[i] * w[j];
        }
        __syncthreads();
    }
    #pragma unroll
    for (int i = 0; i < 8; i++) {
        int gm = row0 + ty * 8 + i;
        __hip_bfloat16* dst = proj + (size_t)gm * 1536 + col0 + tx * 8;
        #pragma unroll
        for (int j = 0; j < 8; j++)
            dst[j] = __float2bfloat16(acc[i][j] + bias[tx * 8 + j]);
    }
}

// ---------------- recur weight repack (both layers): slab[(ld*128+jb)] ----------------
__global__ __launch_bounds__(256)
void repack_kernel(const float* __restrict__ Whh, const float* __restrict__ Whr,
                   float* __restrict__ slabs)
{
    const int blk = blockIdx.x;           // 0..511 = ld*128 + jb
    const int ld = blk >> 7, jb = blk & 127;
    const float* WhhL = Whh + (size_t)ld * 512 * 1024;
    const float* WhrL = Whr + (size_t)ld * 512 * 512;
    float* out = slabs + (size_t)blk * 6144;
    for (int u = 0; u < 24; u++) {
        int idx = threadIdx.x + u * 256;
        int rec = idx / 12, r3 = idx % 12;
        int g = rec >> 2, cg = rec & 3;
        int e = r3 >> 2, ki = r3 & 3;
        int k = g * 4 + ki, j = jb * 4 + cg;
        float v;
        if (e == 0)      v = WhhL[(size_t)k * 1024 + j];
        else if (e == 1) v = WhhL[(size_t)k * 1024 + 512 + j];
        else             v = WhrL[(size_t)k * 512 + j];
        out[idx] = v;
    }
}

// ---------------- layer-1 input-proj weight repack: islabs[(d*128+cb)] ----------------
__global__ __launch_bounds__(256)
void irepack_kernel(const float* __restrict__ Wxh, const float* __restrict__ Wxr,
                    float* __restrict__ islabs)
{
    const int blk = blockIdx.x;           // 0..255 = d*128 + cb
    const int d = blk >> 7, cb = blk & 127;
    const float* WxhL = Wxh + (size_t)(2 + d) * 512 * 1024;
    const float* WxrL = Wxr + (size_t)(2 + d) * 512 * 512;
    float* out = islabs + (size_t)blk * 6144;
    for (int u = 0; u < 24; u++) {
        int idx = threadIdx.x + u * 256;
        int rec = idx / 12, r3 = idx % 12;
        int g = rec >> 2, cg = rec & 3;
        int e = r3 >> 2, ki = r3 & 3;
        int k = g * 4 + ki, c = cb * 12 + cg * 3 + e;
        out[idx] = (c < 1024) ? WxhL[(size_t)k * 1024 + c]
                              : WxrL[(size_t)k * 512 + (c - 1024)];
    }
}

#define AG __HIP_MEMORY_SCOPE_AGENT

// GEMV partial: 3 accumulators over this thread's k-half, weights from LDS.
__device__ __forceinline__ void gemv3(const float* __restrict__ wlds, const float* hrow,
                                      int kh, int cg, float& a0, float& a1, float& a2)
{
    #pragma unroll 8
    for (int gg = 0; gg < 64; gg++) {
        int g = kh * 64 + gg;
        float4 h4 = *(const float4*)(hrow + g * 4);
        const float4* wp = (const float4*)wlds + (size_t)(g * 4 + cg) * 3;
        float4 w0 = wp[0], w1 = wp[1], w2 = wp[2];
        a0 += h4.x*w0.x + h4.y*w0.y + h4.z*w0.z + h4.w*w0.w;
        a1 += h4.x*w1.x + h4.y*w1.y + h4.z*w1.z + h4.w*w1.w;
        a2 += h4.x*w2.x + h4.y*w2.y + h4.z*w2.z + h4.w*w2.w;
    }
    a0 += __shfl_xor(a0, 4, 64);
    a1 += __shfl_xor(a1, 4, 64);
    a2 += __shfl_xor(a2, 4, 64);
}

// ---------------- persistent pipeline v2 ----------------
__global__ __launch_bounds__(256, 3)
void persist_kernel(const __hip_bfloat16* __restrict__ proj0, float* __restrict__ seq0,
                    const float* __restrict__ rslabs, const float* __restrict__ islabs,
                    float* __restrict__ p1, float* __restrict__ h1ring,
                    float* __restrict__ fcin,
                    const float* __restrict__ bhh, const float* __restrict__ bhr,
                    const float* __restrict__ bxh, const float* __restrict__ bxr,
                    int* __restrict__ arrive)
{
    __shared__ __align__(16) float wlds[6144];
    const int blk = blockIdx.x, tid = threadIdx.x;
    const int role = blk >> 8;            // 0=A:L0-recur, 1=B:L1-recur, 2=C:L1-inproj
    const int d  = (blk >> 7) & 1;
    const int jb = blk & 127;
    const int cg = tid & 3, kh = (tid >> 2) & 1, b = tid >> 3;
    const int j  = jb * 4 + cg;

    // ---- stage this block's 24KB weight slab into LDS (once) ----
    {
        const float4* slab = (role == 2)
            ? (const float4*)(islabs + (size_t)(d * 128 + jb) * 6144)
            : (const float4*)(rslabs + (size_t)(((role == 0 ? 0 : 2) + d) * 128 + jb) * 6144);
        #pragma unroll
        for (int v = 0; v < 6; v++) {
            int id = tid + v * 256;
            *(float4*)&wlds[id * 4] = slab[id];
        }
    }
    // ---- invariant biases ----
    const int ld = (role == 0 ? 0 : 2) + d;
    float bz = 0.f, brr = 0.f, bgg = 0.f, bi0 = 0.f, bi1 = 0.f, bi2 = 0.f;
    const int c0 = jb * 12 + cg * 3;
    if (role < 2) {
        bz  = bhh[ld * 1024 + j];
        brr = bhh[ld * 1024 + 512 + j];
        bgg = bhr[ld * 512 + j];
    } else {
        float bv[3];
        #pragma unroll
        for (int e = 0; e < 3; e++) {
            int c = c0 + e;
            bv[e] = (c < 1024) ? bxh[(size_t)(2 + d) * 1024 + c]
                               : bxr[(size_t)(2 + d) * 512 + (c - 1024)];
        }
        bi0 = bv[0]; bi1 = bv[1]; bi2 = bv[2];
    }
    __syncthreads();

    for (int t = 0; t < 130; t++) {
        if (role == 0) {
            // ---- layer 0 recurrence, step t ----
            if (t <= 127) {
                float az = 0.f, ar = 0.f, ag = 0.f, hself = 0.f;
                if (t > 0) {
                    const float* hrow = seq0 + (size_t)(d * 128 + (t - 1)) * 32 * 512 + (size_t)b * 512;
                    gemv3(wlds, hrow, kh, cg, az, ar, ag);
                    hself = hrow[j];
                }
                const __hip_bfloat16* pp = proj0 + (size_t)(d * 128 + t) * 32 * 1536 + (size_t)b * 1536;
                float pz = __bfloat162float(pp[j]);
                float pr = __bfloat162float(pp[512 + j]);
                float pg = __bfloat162float(pp[1024 + j]);
                float z  = 1.f / (1.f + __expf(-(az + pz + bz)));
                float r  = 1.f / (1.f + __expf(-(ar + pr + brr)));
                float gt = tanhf((ag + bgg) * r + pg);
                float hn = z * hself + (1.f - z) * gt;
                if (kh == 0)
                    __hip_atomic_store(&seq0[(size_t)(d * 128 + t) * 32 * 512 + (size_t)b * 512 + j],
                                       hn, __ATOMIC_RELAXED, AG);
            }
        } else if (role == 1) {
            // ---- layer 1 recurrence, step t1 = t-2 ----
            const int t1 = t - 2;
            if (t1 >= 0) {
                float az = 0.f, ar = 0.f, ag = 0.f, hself = 0.f;
                if (t1 > 0) {
                    const float* hrow = h1ring + (size_t)((((t1 - 1) & 1) * 2) + d) * 32 * 512 + (size_t)b * 512;
                    gemv3(wlds, hrow, kh, cg, az, ar, ag);
                    hself = hrow[j];
                }
                const float* pp = p1 + (size_t)(((t1 & 1) * 2) + d) * 32 * 1536 + (size_t)b * 1536;
                float z  = 1.f / (1.f + __expf(-(az + pp[j] + bz)));
                float r  = 1.f / (1.f + __expf(-(ar + pp[512 + j] + brr)));
                float gt = tanhf((ag + bgg) * r + pp[1024 + j]);
                float hn = z * hself + (1.f - z) * gt;
                if (kh == 0) {
                    __hip_atomic_store(&h1ring[(size_t)(((t1 & 1) * 2) + d) * 32 * 512 + (size_t)b * 512 + j],
                                       hn, __ATOMIC_RELAXED, AG);
                    if (d == 0 && t1 == 127)
                        __hip_atomic_store(&fcin[(size_t)b * 512 + j], hn, __ATOMIC_RELAXED, AG);
                    if (d == 1 && t1 == 0)
                        __hip_atomic_store(&fcin[32 * 512 + (size_t)b * 512 + j], hn, __ATOMIC_RELAXED, AG);
                }
            }
        } else {
            // ---- layer 1 input proj, step tp = t-1 ----
            const int tp = t - 1;
            if (tp >= 0 && tp <= 127) {
                const float* xrow = seq0 + (size_t)(d * 128 + tp) * 32 * 512 + (size_t)b * 512;
                float a0 = 0.f, a1 = 0.f, a2 = 0.f;
                gemv3(wlds, xrow, kh, cg, a0, a1, a2);
                if (kh == 0) {
                    float* dst = p1 + (size_t)(((tp & 1) * 2) + d) * 32 * 1536 + (size_t)b * 1536 + c0;
                    __hip_atomic_store(&dst[0], a0 + bi0, __ATOMIC_RELAXED, AG);
                    __hip_atomic_store(&dst[1], a1 + bi1, __ATOMIC_RELAXED, AG);
                    __hip_atomic_store(&dst[2], a2 + bi2, __ATOMIC_RELAXED, AG);
                }
            }
        }
        // ---- grid barrier: 1 thread/block; 8 spread counters per tick ----
        if (t < 129) {
            __syncthreads();    // all waves' stores drained (vmcnt) before arrival
            if (tid == 0) {
                int* base = arrive + t * 8;
                __hip_atomic_fetch_add(&base[blk & 7], 1, __ATOMIC_RELEASE, AG);
                int sum;
                do {
                    sum = 0;
                    #pragma unroll
                    for (int i = 0; i < 8; i++)
                        sum += __hip_atomic_load(&base[i], __ATOMIC_RELAXED, AG);
                    if (sum < 768) __builtin_amdgcn_s_sleep(8);
                } while (sum < 768);
                // acquire: one buffer_inv per block per tick (drop stale clean L2 lines)
                (void)__hip_atomic_load(&base[0], __ATOMIC_ACQUIRE, AG);
            }
            __syncthreads();
        }
    }
}

// ---------------- final FC ----------------
__global__ __launch_bounds__(256)
void fc_kernel(const float* __restrict__ fcin, const float* __restrict__ Wfc,
               const float* __restrict__ bfc, float* __restrict__ out)
{
    int idx = blockIdx.x * 256 + threadIdx.x;   // 0..16383
    int b = idx >> 9, o = idx & 511;
    const float* catf = fcin + (size_t)b * 512;
    const float* catr = fcin + 32 * 512 + (size_t)b * 512;
    float acc = bfc[o];
    #pragma unroll 8
    for (int k = 0; k < 512; k++) acc += catf[k] * Wfc[(size_t)k * 512 + o];
    #pragma unroll 8
    for (int k = 0; k < 512; k++) acc += catr[k] * Wfc[(size_t)(512 + k) * 512 + o];
    out[(size_t)b * 512 + o] = acc;
}

extern "C" void kernel_launch(void* const* d_in, const int* in_sizes, int n_in,
                              void* d_out, int out_size, void* d_ws, size_t ws_size,
                              hipStream_t stream) {
    (void)in_sizes; (void)n_in; (void)out_size; (void)ws_size;
    const float* x   = (const float*)d_in[0];
    const float* Wxh = (const float*)d_in[1];
    const float* bxh = (const float*)d_in[2];
    const float* Whh = (const float*)d_in[3];
    const float* bhh = (const float*)d_in[4];
    const float* Wxr = (const float*)d_in[5];
    const float* bxr = (const float*)d_in[6];
    const float* Whr = (const float*)d_in[7];
    const float* bhr = (const float*)d_in[8];
    const float* Wfc = (const float*)d_in[9];
    const float* bfc = (const float*)d_in[10];
    float* out = (float*)d_out;

    char* base = (char*)d_ws;
    __hip_bfloat16* proj0 = (__hip_bfloat16*)base;
    float* seq0   = (float*)(base + 25165824);
    float* rslabs = seq0   + 4194304;
    float* islabs = rslabs + 3145728;
    float* p1     = islabs + 1572864;
    float* h1ring = p1     + 196608;
    float* fcin   = h1ring + 65536;
    int*   arrive = (int*)(fcin + 32768);

    hipMemsetAsync(arrive, 0, 2048 * sizeof(int), stream);

    repack_kernel<<<512, 256, 0, stream>>>(Whh, Whr, rslabs);
    irepack_kernel<<<256, 256, 0, stream>>>(Wxh, Wxr, islabs);

    dim3 pgrid(12, 64);
    proj_kernel<<<pgrid, 256, 0, stream>>>(x, Wxh, bxh, Wxr, bxr, proj0);

    persist_kernel<<<768, 256, 0, stream>>>(proj0, seq0, rslabs, islabs, p1,
                                            h1ring, fcin, bhh, bhr, bxh, bxr, arrive);

    fc_kernel<<<64, 256, 0, stream>>>(fcin, Wfc, bfc, out);
}